// Round 1
// baseline (168.580 us; speedup 1.0000x reference)
//
#include <hip/hip_runtime.h>

#define ALPHA 0.2f

typedef __attribute__((ext_vector_type(8))) short short8;
typedef __attribute__((ext_vector_type(16))) float f32x16;

__device__ __forceinline__ unsigned short f2bf(float f) {
  unsigned int u = __float_as_uint(f);
  u = (u + 0x7fffu + ((u >> 16) & 1u)) >> 16;   // RNE, finite inputs only
  return (unsigned short)u;
}

// ---------------------------------------------------------------------------
// Kernel 1: f = X @ W^T + b  (fp32 SGEMM, 128x128 tile, 8x8/thread)
// Also emits: ft (bf16, layout [b][n/16][h][c][n%16]) and s_src/s_dst ([b][h][n], f32)
// ---------------------------------------------------------------------------
__global__ __launch_bounds__(256) void gat_k1(
    const float* __restrict__ X, const float* __restrict__ W,
    const float* __restrict__ bias, const float* __restrict__ a,
    unsigned short* __restrict__ ft, float* __restrict__ ssrc,
    float* __restrict__ sdst)
{
  __shared__ float Xs[8][128];
  __shared__ float Ws[8][128];
  const int tid = threadIdx.x;
  const int tx = tid & 15, ty = tid >> 4;
  const int m0 = blockIdx.x * 128;       // global row (= b*2048 + n), tiles stay within one b
  const int c0 = blockIdx.y * 128;       // output column tile

  float acc[8][8];
#pragma unroll
  for (int r = 0; r < 8; ++r)
#pragma unroll
    for (int j = 0; j < 8; ++j) acc[r][j] = 0.f;

  const int lrow = tid >> 1;             // 0..127
  const int kk0 = (tid & 1) * 4;
  const float* Xp = X + (size_t)(m0 + lrow) * 256 + kk0;
  const float* Wp = W + (size_t)(c0 + lrow) * 256 + kk0;

  for (int kc = 0; kc < 256; kc += 8) {
    float4 xv = *(const float4*)(Xp + kc);
    float4 wv = *(const float4*)(Wp + kc);
    __syncthreads();
    Xs[kk0 + 0][lrow] = xv.x; Xs[kk0 + 1][lrow] = xv.y;
    Xs[kk0 + 2][lrow] = xv.z; Xs[kk0 + 3][lrow] = xv.w;
    Ws[kk0 + 0][lrow] = wv.x; Ws[kk0 + 1][lrow] = wv.y;
    Ws[kk0 + 2][lrow] = wv.z; Ws[kk0 + 3][lrow] = wv.w;
    __syncthreads();
#pragma unroll
    for (int kk = 0; kk < 8; ++kk) {
      float av[8], wv8[8];
#pragma unroll
      for (int r = 0; r < 8; ++r) av[r] = Xs[kk][ty * 8 + r];
#pragma unroll
      for (int j = 0; j < 8; ++j) wv8[j] = Ws[kk][tx * 8 + j];
#pragma unroll
      for (int r = 0; r < 8; ++r)
#pragma unroll
        for (int j = 0; j < 8; ++j) acc[r][j] = fmaf(av[r], wv8[j], acc[r][j]);
    }
  }

  const int b = m0 >> 11;
  const int nloc0 = (m0 & 2047) + ty * 8;     // n within batch, 8 consecutive rows
  const int cg0 = c0 + tx * 8;                // 8 consecutive cols, within one head
  const int h = cg0 >> 6;
  const int cb = cg0 & 63;

  float bv[8], av_s[8], av_d[8];
#pragma unroll
  for (int j = 0; j < 8; ++j) {
    bv[j]   = bias[cg0 + j];
    av_s[j] = a[h * 128 + cb + j];
    av_d[j] = a[h * 128 + 64 + cb + j];
  }
#pragma unroll
  for (int r = 0; r < 8; ++r)
#pragma unroll
    for (int j = 0; j < 8; ++j) acc[r][j] += bv[j];

  // ft writes: for each col j, 8 consecutive-n bf16 values -> one 16B store
  const int jt = nloc0 >> 4;
  const int ni = nloc0 & 15;                  // 0 or 8
#pragma unroll
  for (int j = 0; j < 8; ++j) {
    unsigned int u[4];
#pragma unroll
    for (int q = 0; q < 4; ++q) {
      unsigned int lo = f2bf(acc[2 * q + 0][j]);
      unsigned int hi = f2bf(acc[2 * q + 1][j]);
      u[q] = lo | (hi << 16);
    }
    size_t off = ((((size_t)b * 128 + jt) * 4 + h) * 64 + (cb + j)) * 16 + ni;
    *(uint4*)(ft + off) = make_uint4(u[0], u[1], u[2], u[3]);
  }

  // s_src / s_dst partials, reduced over the 8 lanes covering this head's cols
  float sp[8], dp[8];
#pragma unroll
  for (int r = 0; r < 8; ++r) {
    float s = 0.f, d = 0.f;
#pragma unroll
    for (int j = 0; j < 8; ++j) {
      s = fmaf(acc[r][j], av_s[j], s);
      d = fmaf(acc[r][j], av_d[j], d);
    }
    sp[r] = s; dp[r] = d;
  }
#pragma unroll
  for (int off = 1; off < 8; off <<= 1) {
#pragma unroll
    for (int r = 0; r < 8; ++r) {
      sp[r] += __shfl_xor(sp[r], off);
      dp[r] += __shfl_xor(dp[r], off);
    }
  }
  if ((tx & 7) == 0) {
    float* sb = ssrc + ((size_t)b * 4 + h) * 2048 + nloc0;
    float* db = sdst + ((size_t)b * 4 + h) * 2048 + nloc0;
#pragma unroll
    for (int r = 0; r < 8; ++r) { sb[r] = sp[r]; db[r] = dp[r]; }
  }
}

// ---------------------------------------------------------------------------
// Kernel 2: fused mask + leaky-relu + softmax + PV (bf16 MFMA 32x32x16)
// Block: 64 i-rows, all 4 heads for one b. 512 thr = 8 waves = (head, rowblock).
// ---------------------------------------------------------------------------
__global__ __launch_bounds__(512) void gat_k2(
    const int* __restrict__ adj, const unsigned short* __restrict__ ft,
    const float* __restrict__ ssrc, const float* __restrict__ sdst,
    float* __restrict__ out)
{
  __shared__ float sd[4][2048];                     // s_dst for all heads, 32 KB
  __shared__ __align__(16) unsigned short ftile[256 * 20];  // [h*64+c][16j], pitch 20 elems (40B)
  __shared__ __align__(8) unsigned char adjb[64 * 24];      // [i_local][16j], pitch 24B

  const int tid = threadIdx.x;
  const int b = blockIdx.x & 7;                     // XCD-pinning: one b per XCD
  const int itile = blockIdx.x >> 3;
  const int i0 = itile * 64;
  const int w = tid >> 6;
  const int h = w & 3;
  const int rb = w >> 2;
  const int lane = tid & 63;
  const int l31 = lane & 31;
  const int kh = lane >> 5;                         // k-half (0/1)

  // stage s_dst (contiguous 32 KB for this b)
  {
    const float4* src = (const float4*)(sdst + (size_t)b * 4 * 2048);
    float4* dst = (float4*)(&sd[0][0]);
#pragma unroll
    for (int q = 0; q < 4; ++q) dst[tid + q * 512] = src[tid + q * 512];
  }
  const float si = ssrc[((size_t)b * 4 + h) * 2048 + i0 + rb * 32 + l31];

  f32x16 acc0, acc1;
#pragma unroll
  for (int q = 0; q < 16; ++q) { acc0[q] = 0.f; acc1[q] = 0.f; }
  float lsum = 0.f;

  __syncthreads();

  const size_t adjbase = (size_t)b * 2048 * 2048;

  for (int jt = 0; jt < 128; ++jt) {
    const int j0 = jt * 16;
    // ---- stage f-tile: contiguous 8 KB chunk -> LDS (pitch 40B) ----
    {
      const uint4* src = (const uint4*)(ft + ((size_t)b * 128 + jt) * 4096);
      uint4 v = src[tid];
      const int row = tid >> 1, halfq = tid & 1;
      uint2* d = (uint2*)((char*)ftile + row * 40 + halfq * 16);
      d[0] = make_uint2(v.x, v.y);
      d[1] = make_uint2(v.z, v.w);
    }
    // ---- stage adj as bytes ----
    {
      const int row = tid >> 3, jo = (tid & 7) * 2;
      int2 av = *(const int2*)(adj + adjbase + (size_t)(i0 + row) * 2048 + j0 + jo);
      unsigned short pk = (unsigned short)((av.x ? 1u : 0u) | (av.y ? 0x100u : 0u));
      *(unsigned short*)(adjb + row * 24 + jo) = pk;
    }
    __syncthreads();

    // ---- compute ----
    const float4 t0 = *(const float4*)(&sd[h][j0 + kh * 8]);
    const float4 t1 = *(const float4*)(&sd[h][j0 + kh * 8 + 4]);
    uint2 ab = *(const uint2*)(adjb + (rb * 32 + l31) * 24 + kh * 8);

    float tj[8] = {t0.x, t0.y, t0.z, t0.w, t1.x, t1.y, t1.z, t1.w};
    union { unsigned short e[8]; short8 v; } af;
#pragma unroll
    for (int q = 0; q < 8; ++q) {
      float x = si + tj[q];
      float y = x > 0.f ? x : ALPHA * x;
      float e = __expf(y);
      unsigned int byte = (q < 4) ? ((ab.x >> (8 * q)) & 0xffu)
                                  : ((ab.y >> (8 * (q - 4))) & 0xffu);
      e = byte ? e : 0.f;
      unsigned short eb = f2bf(e);
      af.e[q] = eb;
      lsum += __uint_as_float(((unsigned int)eb) << 16);  // denominator from same rounded weights
    }

    const char* fbase = (const char*)ftile;
    const int cA = h * 64 + l31;
    uint2 u0 = *(const uint2*)(fbase + cA * 40 + kh * 16);
    uint2 u1 = *(const uint2*)(fbase + cA * 40 + kh * 16 + 8);
    uint2 v0 = *(const uint2*)(fbase + (cA + 32) * 40 + kh * 16);
    uint2 v1 = *(const uint2*)(fbase + (cA + 32) * 40 + kh * 16 + 8);
    union { unsigned int u[4]; short8 v; } bf0, bf1;
    bf0.u[0] = u0.x; bf0.u[1] = u0.y; bf0.u[2] = u1.x; bf0.u[3] = u1.y;
    bf1.u[0] = v0.x; bf1.u[1] = v0.y; bf1.u[2] = v1.x; bf1.u[3] = v1.y;

    acc0 = __builtin_amdgcn_mfma_f32_32x32x16_bf16(af.v, bf0.v, acc0, 0, 0, 0);
    acc1 = __builtin_amdgcn_mfma_f32_32x32x16_bf16(af.v, bf1.v, acc1, 0, 0, 0);

    __syncthreads();
  }

  // ---- epilogue: normalize and store ----
  lsum += __shfl_xor(lsum, 32);            // both k-halves -> full row sum
  float rinv = 1.0f / lsum;                // lane holds 1/L for row l31
  float* obase = out + ((size_t)(b * 2048 + i0 + rb * 32)) * 256 + h * 64;
#pragma unroll
  for (int reg = 0; reg < 16; ++reg) {
    int row = (reg & 3) + 8 * (reg >> 2) + 4 * kh;
    float ri = __shfl(rinv, row);
    obase[(size_t)row * 256 + l31]      = acc0[reg] * ri;
    obase[(size_t)row * 256 + 32 + l31] = acc1[reg] * ri;
  }
}

// ---------------------------------------------------------------------------
extern "C" void kernel_launch(void* const* d_in, const int* in_sizes, int n_in,
                              void* d_out, int out_size, void* d_ws, size_t ws_size,
                              hipStream_t stream) {
  const float* X    = (const float*)d_in[0];   // (8,2048,256) f32
  const int*   adj  = (const int*)d_in[1];     // (8,2048,2048) i32
  const float* W    = (const float*)d_in[2];   // (256,256) f32
  const float* bias = (const float*)d_in[3];   // (256,) f32
  const float* a    = (const float*)d_in[4];   // (4,128) f32
  float* out = (float*)d_out;

  unsigned short* ft = (unsigned short*)d_ws;                    // 8 MB bf16
  float* ssrc = (float*)((char*)d_ws + 8388608);                 // 256 KB
  float* sdst = ssrc + 8 * 4 * 2048;                             // 256 KB

  gat_k1<<<dim3(128, 2, 1), 256, 0, stream>>>(X, W, bias, a, ft, ssrc, sdst);
  gat_k2<<<dim3(256, 1, 1), 512, 0, stream>>>(adj, ft, ssrc, sdst, out);
}

// Round 2
// 111.017 us; speedup vs baseline: 1.5185x; 1.5185x over previous
//
#include <hip/hip_runtime.h>

#define LOG2E 1.4426950408889634f

typedef __attribute__((ext_vector_type(8))) short short8;
typedef __attribute__((ext_vector_type(16))) float f32x16;

__device__ __forceinline__ unsigned short f2bf(float f) {
  unsigned int u = __float_as_uint(f);
  u = (u + 0x7fffu + ((u >> 16) & 1u)) >> 16;   // RNE, finite inputs only
  return (unsigned short)u;
}

// ---------------------------------------------------------------------------
// Kernel 1: f = X @ W^T + b  (fp32 SGEMM, 128x128 tile, 8x8/thread)
// Emits: ft (bf16, layout [b][n/16][h][c][n%16]) and s_src/s_dst ([b][h][n],
// f32, PRE-SCALED by log2(e) so k2 can use raw v_exp_f32).
// ---------------------------------------------------------------------------
__global__ __launch_bounds__(256) void gat_k1(
    const float* __restrict__ X, const float* __restrict__ W,
    const float* __restrict__ bias, const float* __restrict__ a,
    unsigned short* __restrict__ ft, float* __restrict__ ssrc,
    float* __restrict__ sdst)
{
  __shared__ float Xs[8][128];
  __shared__ float Ws[8][128];
  const int tid = threadIdx.x;
  const int tx = tid & 15, ty = tid >> 4;
  const int m0 = blockIdx.x * 128;       // global row (= b*2048 + n)
  const int c0 = blockIdx.y * 128;       // output column tile

  float acc[8][8];
#pragma unroll
  for (int r = 0; r < 8; ++r)
#pragma unroll
    for (int j = 0; j < 8; ++j) acc[r][j] = 0.f;

  const int lrow = tid >> 1;             // 0..127
  const int kk0 = (tid & 1) * 4;
  const float* Xp = X + (size_t)(m0 + lrow) * 256 + kk0;
  const float* Wp = W + (size_t)(c0 + lrow) * 256 + kk0;

  for (int kc = 0; kc < 256; kc += 8) {
    float4 xv = *(const float4*)(Xp + kc);
    float4 wv = *(const float4*)(Wp + kc);
    __syncthreads();
    Xs[kk0 + 0][lrow] = xv.x; Xs[kk0 + 1][lrow] = xv.y;
    Xs[kk0 + 2][lrow] = xv.z; Xs[kk0 + 3][lrow] = xv.w;
    Ws[kk0 + 0][lrow] = wv.x; Ws[kk0 + 1][lrow] = wv.y;
    Ws[kk0 + 2][lrow] = wv.z; Ws[kk0 + 3][lrow] = wv.w;
    __syncthreads();
#pragma unroll
    for (int kk = 0; kk < 8; ++kk) {
      float av[8], wv8[8];
#pragma unroll
      for (int r = 0; r < 8; ++r) av[r] = Xs[kk][ty * 8 + r];
#pragma unroll
      for (int j = 0; j < 8; ++j) wv8[j] = Ws[kk][tx * 8 + j];
#pragma unroll
      for (int r = 0; r < 8; ++r)
#pragma unroll
        for (int j = 0; j < 8; ++j) acc[r][j] = fmaf(av[r], wv8[j], acc[r][j]);
    }
  }

  const int b = m0 >> 11;
  const int nloc0 = (m0 & 2047) + ty * 8;
  const int cg0 = c0 + tx * 8;
  const int h = cg0 >> 6;
  const int cb = cg0 & 63;

  float bv[8], av_s[8], av_d[8];
#pragma unroll
  for (int j = 0; j < 8; ++j) {
    bv[j]   = bias[cg0 + j];
    av_s[j] = a[h * 128 + cb + j];
    av_d[j] = a[h * 128 + 64 + cb + j];
  }
#pragma unroll
  for (int r = 0; r < 8; ++r)
#pragma unroll
    for (int j = 0; j < 8; ++j) acc[r][j] += bv[j];

  const int jt = nloc0 >> 4;
  const int ni = nloc0 & 15;
#pragma unroll
  for (int j = 0; j < 8; ++j) {
    unsigned int u[4];
#pragma unroll
    for (int q = 0; q < 4; ++q) {
      unsigned int lo = f2bf(acc[2 * q + 0][j]);
      unsigned int hi = f2bf(acc[2 * q + 1][j]);
      u[q] = lo | (hi << 16);
    }
    size_t off = ((((size_t)b * 128 + jt) * 4 + h) * 64 + (cb + j)) * 16 + ni;
    *(uint4*)(ft + off) = make_uint4(u[0], u[1], u[2], u[3]);
  }

  float sp[8], dp[8];
#pragma unroll
  for (int r = 0; r < 8; ++r) {
    float s = 0.f, d = 0.f;
#pragma unroll
    for (int j = 0; j < 8; ++j) {
      s = fmaf(acc[r][j], av_s[j], s);
      d = fmaf(acc[r][j], av_d[j], d);
    }
    sp[r] = s; dp[r] = d;
  }
#pragma unroll
  for (int off = 1; off < 8; off <<= 1) {
#pragma unroll
    for (int r = 0; r < 8; ++r) {
      sp[r] += __shfl_xor(sp[r], off);
      dp[r] += __shfl_xor(dp[r], off);
    }
  }
  if ((tx & 7) == 0) {
    float* sb = ssrc + ((size_t)b * 4 + h) * 2048 + nloc0;
    float* db = sdst + ((size_t)b * 4 + h) * 2048 + nloc0;
#pragma unroll
    for (int r = 0; r < 8; ++r) { sb[r] = sp[r] * LOG2E; db[r] = dp[r] * LOG2E; }
  }
}

// ---------------------------------------------------------------------------
// Kernel 2: fused mask + leaky-relu + softmax + PV (bf16 MFMA 32x32x16)
// Grid 512 blocks (b = idx&7 -> XCD pinned, itile = idx>>3, 32 i-rows each).
// 512 thr = 8 waves = (head h, j-parity p). Wave (h,p) handles j-halves of
// each 32-j step; partial acc/denominator combined in LDS at the epilogue.
// Double-buffered LDS staging, ONE barrier per step (64 total).
// ---------------------------------------------------------------------------
#define FT_PITCH 72                      // (h,c) row: 32 j * 2B + 8B pad (2-way banks)
#define FT_BYTES (256 * FT_PITCH)        // 18432
#define ADJ_PITCH 40                     // 32 j bytes + 8 pad
#define ADJ_BYTES (32 * ADJ_PITCH)       // 1280

__global__ __launch_bounds__(512, 4) void gat_k2(
    const int* __restrict__ adj, const unsigned short* __restrict__ ft,
    const float* __restrict__ ssrc, const float* __restrict__ sdst,
    float* __restrict__ out)
{
  __shared__ __align__(16) unsigned char lds[2 * FT_BYTES + 2 * ADJ_BYTES]; // 39424 B
  unsigned char* ftile = lds;
  unsigned char* adjb  = lds + 2 * FT_BYTES;

  const int tid = threadIdx.x;
  const int b = blockIdx.x & 7;
  const int itile = blockIdx.x >> 3;     // 0..63
  const int i0 = itile * 32;
  const int w = tid >> 6;
  const int h = w >> 1;
  const int p = w & 1;
  const int lane = tid & 63;
  const int l31 = lane & 31;
  const int kh = lane >> 5;

  const float si = ssrc[((size_t)b * 4 + h) * 2048 + i0 + l31];  // *log2e already
  const float* sdh = sdst + ((size_t)b * 4 + h) * 2048;
  const size_t adjbase = (size_t)b * 2048 * 2048 + (size_t)i0 * 2048;

  // ft staging: idx in [0,1024): elem_off = idx*8 ; half=idx&1, row=(idx>>1)&255,
  // q2=idx>>9 ; LDS dest = row*72 + q2*32 + half*16
  auto wft = [&](unsigned char* base, int idx, uint4 v) {
    const int half = idx & 1, row = (idx >> 1) & 255, q2 = idx >> 9;
    unsigned char* d = base + row * FT_PITCH + q2 * 32 + half * 16;
    *(uint2*)d       = make_uint2(v.x, v.y);
    *(uint2*)(d + 8) = make_uint2(v.z, v.w);
  };
  const int arow = tid >> 4, aj = (tid & 15) * 2;

  // ---- prologue: stage step 0 into buffer 0 ----
  {
    const uint4* src = (const uint4*)(ft + ((size_t)b * 128) * 4096);
    uint4 f0 = src[tid], f1 = src[tid + 512];
    int2 av = *(const int2*)(adj + adjbase + (size_t)arow * 2048 + aj);
    wft(ftile, tid, f0);
    wft(ftile, tid + 512, f1);
    unsigned short pk = (unsigned short)((av.x ? 1u : 0u) | (av.y ? 0x100u : 0u));
    *(unsigned short*)(adjb + arow * ADJ_PITCH + aj) = pk;
  }

  f32x16 acc0, acc1;
#pragma unroll
  for (int q = 0; q < 16; ++q) { acc0[q] = 0.f; acc1[q] = 0.f; }
  float lsum = 0.f;

  __syncthreads();

  for (int s = 0; s < 64; ++s) {
    const int cur = s & 1;
    // ---- issue next-step global loads (latency hides under compute) ----
    const int sn = (s < 63) ? s + 1 : 63;
    const uint4* src = (const uint4*)(ft + ((size_t)b * 128 + (size_t)sn * 2) * 4096);
    uint4 f0 = src[tid], f1 = src[tid + 512];
    int2 av = *(const int2*)(adj + adjbase + (size_t)arow * 2048 + sn * 32 + aj);

    // ---- compute current step ----
    const unsigned char* fb  = ftile + cur * FT_BYTES;
    const unsigned char* ab_ = adjb + cur * ADJ_BYTES;
    const int jloc = p * 16 + kh * 8;          // this lane's 8 j's within the step
    const int j0 = s * 32;

    uint2 am = *(const uint2*)(ab_ + l31 * ADJ_PITCH + jloc);
    const float* tp = sdh + j0 + jloc;
    float4 t0 = *(const float4*)tp;
    float4 t1 = *(const float4*)(tp + 4);
    float tj[8] = {t0.x, t0.y, t0.z, t0.w, t1.x, t1.y, t1.z, t1.w};

    float e[8];
#pragma unroll
    for (int q = 0; q < 8; ++q) {
      float x = si + tj[q];
      float y = fmaxf(x, 0.2f * x);            // leaky-relu (log2 units)
      float ev = __builtin_amdgcn_exp2f(y);
      unsigned byte = (q < 4) ? ((am.x >> (8 * q)) & 0xffu)
                              : ((am.y >> (8 * (q - 4))) & 0xffu);
      ev = byte ? ev : 0.f;
      e[q] = ev;
      lsum += ev;
    }
    union { unsigned u[4]; short8 v; } af;
#pragma unroll
    for (int q2 = 0; q2 < 4; ++q2) {
      unsigned r;
      asm("v_cvt_pk_bf16_f32 %0, %1, %2" : "=v"(r) : "v"(e[2 * q2]), "v"(e[2 * q2 + 1]));
      af.u[q2] = r;
    }

    const unsigned char* r0 = fb + (h * 64 + l31) * FT_PITCH + jloc * 2;
    const unsigned char* r1 = fb + (h * 64 + l31 + 32) * FT_PITCH + jloc * 2;
    union { unsigned u[4]; short8 v; } b0, b1;
    uint2 x0 = *(const uint2*)r0, x1 = *(const uint2*)(r0 + 8);
    uint2 y0 = *(const uint2*)r1, y1 = *(const uint2*)(r1 + 8);
    b0.u[0] = x0.x; b0.u[1] = x0.y; b0.u[2] = x1.x; b0.u[3] = x1.y;
    b1.u[0] = y0.x; b1.u[1] = y0.y; b1.u[2] = y1.x; b1.u[3] = y1.y;

    acc0 = __builtin_amdgcn_mfma_f32_32x32x16_bf16(af.v, b0.v, acc0, 0, 0, 0);
    acc1 = __builtin_amdgcn_mfma_f32_32x32x16_bf16(af.v, b1.v, acc1, 0, 0, 0);

    // ---- write next-step staging into the other buffer ----
    if (s < 63) {
      unsigned char* fdst = ftile + (cur ^ 1) * FT_BYTES;
      wft(fdst, tid, f0);
      wft(fdst, tid + 512, f1);
      unsigned short pk = (unsigned short)((av.x ? 1u : 0u) | (av.y ? 0x100u : 0u));
      *(unsigned short*)(adjb + (cur ^ 1) * ADJ_BYTES + arow * ADJ_PITCH + aj) = pk;
    }
    __syncthreads();
  }

  // ---- epilogue: combine p=0/p=1 partials, normalize, store ----
  float lsum2 = lsum + __shfl_xor(lsum, 32);       // fold kh halves -> p-partial row sum
  float* ep = (float*)lds;                          // [h][32 rows][64 cols] f32 = 32 KB
  float* el = (float*)(lds + 32768);                // [h][32] f32
  if (p == 1) {
#pragma unroll
    for (int reg = 0; reg < 16; ++reg) {
      const int row = (reg & 3) + 8 * (reg >> 2) + 4 * kh;
      ep[(h * 32 + row) * 64 + l31]      = acc0[reg];
      ep[(h * 32 + row) * 64 + l31 + 32] = acc1[reg];
    }
    if (lane < 32) el[h * 32 + l31] = lsum2;
  }
  __syncthreads();
  if (p == 0) {
    const float L = lsum2 + el[h * 32 + l31];
    const float rinv = 1.0f / L;
    float* ob = out + ((size_t)(b * 2048 + i0)) * 256 + h * 64;
#pragma unroll
    for (int reg = 0; reg < 16; ++reg) {
      const int row = (reg & 3) + 8 * (reg >> 2) + 4 * kh;
      const float ri = __shfl(rinv, row);
      const float o0 = (acc0[reg] + ep[(h * 32 + row) * 64 + l31]) * ri;
      const float o1 = (acc1[reg] + ep[(h * 32 + row) * 64 + l31 + 32]) * ri;
      ob[(size_t)row * 256 + l31]      = o0;
      ob[(size_t)row * 256 + l31 + 32] = o1;
    }
  }
}

// ---------------------------------------------------------------------------
extern "C" void kernel_launch(void* const* d_in, const int* in_sizes, int n_in,
                              void* d_out, int out_size, void* d_ws, size_t ws_size,
                              hipStream_t stream) {
  const float* X    = (const float*)d_in[0];   // (8,2048,256) f32
  const int*   adj  = (const int*)d_in[1];     // (8,2048,2048) i32
  const float* W    = (const float*)d_in[2];   // (256,256) f32
  const float* bias = (const float*)d_in[3];   // (256,) f32
  const float* a    = (const float*)d_in[4];   // (4,128) f32
  float* out = (float*)d_out;

  unsigned short* ft = (unsigned short*)d_ws;                    // 8 MB bf16
  float* ssrc = (float*)((char*)d_ws + 8388608);                 // 256 KB
  float* sdst = ssrc + 8 * 4 * 2048;                             // 256 KB

  gat_k1<<<dim3(128, 2, 1), 256, 0, stream>>>(X, W, bias, a, ft, ssrc, sdst);
  gat_k2<<<dim3(512, 1, 1), 512, 0, stream>>>(adj, ft, ssrc, sdst, out);
}